// Round 7
// baseline (127.417 us; speedup 1.0000x reference)
//
#include <hip/hip_runtime.h>
#include <cfloat>

// Emu3 VQ-VAE vector quantizer argmin (exact-rounding match to numpy ref):
//   x [9216,4] f32 (channels-last gather from [1,4,4,48,48])
//   e [32768,4] f32
//   out[n] = argmin_k fl( fl(x2+e2) - 2*fl(dot) ), first-min tie semantics.
//
// Round 7: R6's u64-key/64-bit-shfl path corrupted indices -> reverted to the
// R5-verified math + 32-bit (float,int) shfl reduce. Rotation retested with
// provably-order-safe two-run candidates:
//   per-block start step s0 = blockIdx.x & 63 (512-entry steps);
//   run H: m = s0..63 (ascending k, strict <), run L: m = 0..s0-1 (ascending);
//   merge bL <= bH -> L  (all L ks < all H ks => ties -> lowest k).
// Theory: R3-R5 pinned at ~83us regardless of VALU work => lockstep codebook
// sweep hotspots the same L2 lines/channels chip-wide; rotation spreads
// concurrent requests over the full 512 KB.

typedef float v2f __attribute__((ext_vector_type(2)));

#define ROWS   12
#define RP     6
#define BLOCK  256
#define NK     32768
#define EPT    2
#define CHUNK  (BLOCK * EPT)      // 512 entries per step
#define NSTEP  (NK / CHUNK)       // 64

__device__ __forceinline__ float rlf(float v) {
    return __builtin_bit_cast(float,
        __builtin_amdgcn_readfirstlane(__builtin_bit_cast(int, v)));
}

// compute one 512-entry chunk from BUF (loaded with step M) into (BV, MV)
#define CC(BUF, M, BV, MV) do {                                               \
    _Pragma("unroll")                                                         \
    for (int j = 0; j < EPT; ++j) {                                           \
        float4 e = BUF[j];                                                    \
        float e2 = __fadd_rn(__fadd_rn(__fadd_rn(__fmul_rn(e.x, e.x),         \
                                                 __fmul_rn(e.y, e.y)),        \
                                       __fmul_rn(e.z, e.z)),                  \
                             __fmul_rn(e.w, e.w));                            \
        v2f ex = {e.x, e.x}, ey = {e.y, e.y};                                 \
        v2f ez = {e.z, e.z}, ew = {e.w, e.w};                                 \
        v2f e2s = {e2, e2};                                                   \
        int mb = 2 * (M) + j;     /* entry-block index, k = mb*256 + tid */   \
        _Pragma("unroll")                                                     \
        for (int p = 0; p < RP; ++p) {                                        \
            v2f dot = xp0[p] * ex;                                            \
            dot = __builtin_elementwise_fma(xp1[p], ey, dot);                 \
            dot = __builtin_elementwise_fma(xp2[p], ez, dot);                 \
            dot = __builtin_elementwise_fma(xp3[p], ew, dot);                 \
            v2f t1 = x2p[p] + e2s;                                            \
            v2f d  = __builtin_elementwise_fma(dot, (v2f){-2.f, -2.f}, t1);   \
            if (d.x < BV[2 * p])     { BV[2 * p] = d.x;     MV[2 * p] = mb; } \
            if (d.y < BV[2 * p + 1]) { BV[2 * p + 1] = d.y; MV[2 * p + 1] = mb; } \
        }                                                                     \
    }                                                                         \
} while (0)

__global__ __launch_bounds__(BLOCK)
__attribute__((amdgpu_waves_per_eu(3, 4)))
void vq_argmin_kernel(const float* __restrict__ hs,
                      const float4* __restrict__ cb,
                      int* __restrict__ out)
{
    __shared__ float sRD[4 * ROWS];
    __shared__ int   sRI[4 * ROWS];

    const int tid = threadIdx.x;
    const int rowbase = blockIdx.x * ROWS;
    const int s0 = blockIdx.x & (NSTEP - 1);   // rotated start step

    // ---- block-uniform x components -> SGPR pairs (packed fp32 operands)
    v2f xp0[RP], xp1[RP], xp2[RP], xp3[RP], x2p[RP];
    #pragma unroll
    for (int p = 0; p < RP; ++p) {
        float c_0[2], c_1[2], c_2[2], c_3[2], q[2];
        #pragma unroll
        for (int h = 0; h < 2; ++h) {
            int n = rowbase + 2 * p + h;
            int t = n / 2304;                 // 2304 = 48*48
            int rem = n - t * 2304;
            const float* ptr = hs + t * 9216 + rem;   // + c*2304 per channel
            float a0 = ptr[0], a1 = ptr[2304], a2 = ptr[4608], a3 = ptr[6912];
            c_0[h] = a0; c_1[h] = a1; c_2[h] = a2; c_3[h] = a3;
            q[h] = __fadd_rn(__fadd_rn(__fadd_rn(__fmul_rn(a0, a0),
                                                 __fmul_rn(a1, a1)),
                                       __fmul_rn(a2, a2)),
                             __fmul_rn(a3, a3));
        }
        xp0[p] = (v2f){rlf(c_0[0]), rlf(c_0[1])};
        xp1[p] = (v2f){rlf(c_1[0]), rlf(c_1[1])};
        xp2[p] = (v2f){rlf(c_2[0]), rlf(c_2[1])};
        xp3[p] = (v2f){rlf(c_3[0]), rlf(c_3[1])};
        x2p[p] = (v2f){rlf(q[0]),  rlf(q[1])};
    }

    float bH[ROWS], bL[ROWS];
    int   mH[ROWS], mL[ROWS];
    #pragma unroll
    for (int r = 0; r < ROWS; ++r) {
        bH[r] = FLT_MAX; bL[r] = FLT_MAX; mH[r] = 0; mL[r] = 0;
    }

    float4 bufA[EPT], bufB[EPT];

    auto ms = [&](int v) {                      // step v in visit order -> m
        int m = v + s0;
        if (m >= NSTEP) m -= NSTEP;
        return m;
    };
    auto load_chunk = [&](float4* buf, int m) {
        const float4* p = cb + m * CHUNK + tid;
        #pragma unroll
        for (int j = 0; j < EPT; ++j) buf[j] = p[j * BLOCK];
    };

    // ---- rotated ping-pong K loop; H run then L run (each ascending in k)
    load_chunk(bufA, ms(0));
    for (int s = 0; s < NSTEP; s += 2) {
        load_chunk(bufB, ms(s + 1));
        {
            int m = ms(s);
            if (s + s0 < NSTEP) { CC(bufA, m, bH, mH); }
            else                { CC(bufA, m, bL, mL); }
        }
        load_chunk(bufA, ms(s + 2 < NSTEP ? s + 2 : 0));  // last: dummy
        {
            int m = ms(s + 1);
            if (s + 1 + s0 < NSTEP) { CC(bufB, m, bH, mH); }
            else                    { CC(bufB, m, bL, mL); }
        }
    }

    // ---- merge runs (tie -> L: all L-run ks < all H-run ks)
    float best[ROWS]; int kk[ROWS];
    #pragma unroll
    for (int r = 0; r < ROWS; ++r) {
        float d; int mb;
        if (bL[r] <= bH[r]) { d = bL[r]; mb = mL[r]; }
        else                { d = bH[r]; mb = mH[r]; }
        best[r] = d;
        kk[r] = mb * BLOCK + tid;
    }

    // ---- wave-level lexicographic (dist, idx) butterfly reduction
    #pragma unroll
    for (int r = 0; r < ROWS; ++r) {
        float d = best[r]; int i = kk[r];
        #pragma unroll
        for (int off = 32; off >= 1; off >>= 1) {
            float d2 = __shfl_xor(d, off, 64);
            int   i2 = __shfl_xor(i, off, 64);
            if (d2 < d || (d2 == d && i2 < i)) { d = d2; i = i2; }
        }
        best[r] = d; kk[r] = i;
    }

    int wave = tid >> 6;
    if ((tid & 63) == 0) {
        #pragma unroll
        for (int r = 0; r < ROWS; ++r) {
            sRD[wave * ROWS + r] = best[r];
            sRI[wave * ROWS + r] = kk[r];
        }
    }
    __syncthreads();

    if (tid < ROWS) {
        float d = sRD[tid]; int i = sRI[tid];
        #pragma unroll
        for (int w = 1; w < 4; ++w) {
            float d2 = sRD[w * ROWS + tid];
            int   i2 = sRI[w * ROWS + tid];
            if (d2 < d || (d2 == d && i2 < i)) { d = d2; i = i2; }
        }
        out[rowbase + tid] = i;
    }
}

extern "C" void kernel_launch(void* const* d_in, const int* in_sizes, int n_in,
                              void* d_out, int out_size, void* d_ws, size_t ws_size,
                              hipStream_t stream)
{
    const float*  hs = (const float*)d_in[0];    // [1,4,4,48,48]
    const float4* cb = (const float4*)d_in[1];   // [32768,4]
    int* out = (int*)d_out;                      // [9216] int32

    const int nrows = 9216;
    dim3 grid(nrows / ROWS), block(BLOCK);
    vq_argmin_kernel<<<grid, block, 0, stream>>>(hs, cb, out);
}

// Round 9
// 125.290 us; speedup vs baseline: 1.0170x; 1.0170x over previous
//
#include <hip/hip_runtime.h>
#include <cfloat>

// Emu3 VQ-VAE vector quantizer argmin (exact-rounding match to numpy ref):
//   x [9216,4] f32 (channels-last gather from [1,4,4,48,48])
//   e [32768,4] f32
//   out[n] = argmin_k fl( fl(x2+e2) - 2*fl(dot) ), first-min tie semantics.
//
// Round 9: traffic attack on the R4-verified skeleton (minimal diff: ROWS
// 9->18 only). Ledger: total L2 codebook traffic = (9216/ROWS)*512KB; R5/R8
// delivered 6.2/9.6 TB/s at identical ~83us -> traffic-proportional L2-stream
// wall (~10 TB/s all-miss-L1, not the 34.5 L1-reuse ubench). ROWS=18 halves
// traffic to 256MB (grid 512 = exactly 2 blocks/CU); VALU issue floor ~36us
// becomes binding. All components (math chain, ping-pong EPT=2,
// launch_bounds(256,2), 32-bit shfl reduce) are R4-verified bit-exact.
// R8's unverified waves_per_eu(6,8)+readfirstlane combo is dropped entirely
// after its launch-state-dependent corruption.

#define ROWS   18
#define BLOCK  256
#define NK     32768
#define EPT    2                  // codebook entries per lane per chunk
#define CHUNK  (BLOCK * EPT)      // 512 entries per chunk
#define NSTEP  (NK / CHUNK)       // 64

__global__ __launch_bounds__(BLOCK, 2)
void vq_argmin_kernel(const float* __restrict__ hs,
                      const float4* __restrict__ cb,
                      int* __restrict__ out)
{
    __shared__ float sRD[4 * ROWS];
    __shared__ int   sRI[4 * ROWS];

    const int tid = threadIdx.x;
    const int rowbase = blockIdx.x * ROWS;

    float xr0[ROWS], xr1[ROWS], xr2[ROWS], xr3[ROWS];
    float x2[ROWS];
    float best[ROWS];
    int   bidx[ROWS];   // entry-block index mb; k = mb*256 + tid

    #pragma unroll
    for (int r = 0; r < ROWS; ++r) {
        int n = rowbase + r;
        int t = n / 2304;                 // 2304 = 48*48
        int rem = n - t * 2304;
        const float* p = hs + t * 9216 + rem;   // + c*2304 per channel
        float a0 = p[0], a1 = p[2304], a2 = p[4608], a3 = p[6912];
        xr0[r] = a0; xr1[r] = a1; xr2[r] = a2; xr3[r] = a3;
        x2[r] = __fadd_rn(__fadd_rn(__fadd_rn(__fmul_rn(a0, a0),
                                              __fmul_rn(a1, a1)),
                                    __fmul_rn(a2, a2)),
                          __fmul_rn(a3, a3));
        best[r] = FLT_MAX;
        bidx[r] = 0;
    }

    float4 bufA[EPT], bufB[EPT];

    auto load_chunk = [&](float4* buf, int s) {
        const float4* p = cb + s * CHUNK + tid;
        #pragma unroll
        for (int j = 0; j < EPT; ++j) buf[j] = p[j * BLOCK];
    };
    auto compute_chunk = [&](const float4* buf, int s) {
        #pragma unroll
        for (int j = 0; j < EPT; ++j) {
            float4 e = buf[j];
            float e2 = __fadd_rn(__fadd_rn(__fadd_rn(__fmul_rn(e.x, e.x),
                                                     __fmul_rn(e.y, e.y)),
                                           __fmul_rn(e.z, e.z)),
                                 __fmul_rn(e.w, e.w));
            int mb = 2 * s + j;           // uniform entry-block index
            #pragma unroll
            for (int r = 0; r < ROWS; ++r) {
                float dot = __builtin_fmaf(xr3[r], e.w,
                            __builtin_fmaf(xr2[r], e.z,
                            __builtin_fmaf(xr1[r], e.y,
                            __fmul_rn(xr0[r], e.x))));
                float t1 = __fadd_rn(x2[r], e2);
                float d  = __builtin_fmaf(dot, -2.0f, t1);
                if (d < best[r]) { best[r] = d; bidx[r] = mb; }
            }
        }
    };

    // ---- ping-pong K loop (ascending k; strict < keeps first-min ties)
    load_chunk(bufA, 0);
    for (int s = 0; s < NSTEP; s += 2) {
        load_chunk(bufB, s + 1);
        compute_chunk(bufA, s);
        load_chunk(bufA, s + 2 < NSTEP ? s + 2 : 0);   // last: dummy reload
        compute_chunk(bufB, s + 1);
    }

    // ---- expand entry-block index -> codebook index
    int kk[ROWS];
    #pragma unroll
    for (int r = 0; r < ROWS; ++r) kk[r] = bidx[r] * BLOCK + tid;

    // ---- wave-level lexicographic (dist, idx) butterfly reduction
    #pragma unroll
    for (int r = 0; r < ROWS; ++r) {
        float d = best[r]; int i = kk[r];
        #pragma unroll
        for (int off = 32; off >= 1; off >>= 1) {
            float d2 = __shfl_xor(d, off, 64);
            int   i2 = __shfl_xor(i, off, 64);
            if (d2 < d || (d2 == d && i2 < i)) { d = d2; i = i2; }
        }
        best[r] = d; kk[r] = i;
    }

    int wave = tid >> 6;
    if ((tid & 63) == 0) {
        #pragma unroll
        for (int r = 0; r < ROWS; ++r) {
            sRD[wave * ROWS + r] = best[r];
            sRI[wave * ROWS + r] = kk[r];
        }
    }
    __syncthreads();

    if (tid < ROWS) {
        float d = sRD[tid]; int i = sRI[tid];
        #pragma unroll
        for (int w = 1; w < 4; ++w) {
            float d2 = sRD[w * ROWS + tid];
            int   i2 = sRI[w * ROWS + tid];
            if (d2 < d || (d2 == d && i2 < i)) { d = d2; i = i2; }
        }
        out[rowbase + tid] = i;
    }
}

extern "C" void kernel_launch(void* const* d_in, const int* in_sizes, int n_in,
                              void* d_out, int out_size, void* d_ws, size_t ws_size,
                              hipStream_t stream)
{
    const float*  hs = (const float*)d_in[0];    // [1,4,4,48,48]
    const float4* cb = (const float4*)d_in[1];   // [32768,4]
    int* out = (int*)d_out;                      // [9216] int32

    const int nrows = 9216;
    dim3 grid(nrows / ROWS), block(BLOCK);       // 512 blocks = 2/CU exact
    vq_argmin_kernel<<<grid, block, 0, stream>>>(hs, cb, out);
}